// Round 17
// baseline (378.766 us; speedup 1.0000x reference)
//
#include <hip/hip_runtime.h>
#include <math.h>

typedef _Float16 half8  __attribute__((ext_vector_type(8)));
typedef _Float16 half4v __attribute__((ext_vector_type(4)));
typedef float    f32x4  __attribute__((ext_vector_type(4)));

__device__ __forceinline__ _Float16 f2h(float f) { return (_Float16)f; }

__device__ __forceinline__ float tanh_fast(float x) {
    float e = __expf(2.f * x);
    return 1.f - 2.f / (e + 1.f);
}

__device__ __forceinline__ half8 cvt8(float4 a, float4 b) {
    half8 h = { f2h(a.x), f2h(a.y), f2h(a.z), f2h(a.w),
                f2h(b.x), f2h(b.y), f2h(b.z), f2h(b.w) };
    return h;
}

// ==================== pack: f32 -> f16, panel layout [K/32][rows][32] ====================
__global__ __launch_bounds__(256) void pack_all(
    const float* __restrict__ att_Wih,  const float* __restrict__ att_Whh,
    const float* __restrict__ lang_Wih, const float* __restrict__ lang_Whh,
    const float* __restrict__ attr_Wq,  const float* __restrict__ obj_Wq,
    const float* __restrict__ rela_Wq,
    const float* __restrict__ h1, const float* __restrict__ fc,
    const float* __restrict__ xt, const float* __restrict__ h0,
    _Float16* __restrict__ attW16, _Float16* __restrict__ langW16,
    _Float16* __restrict__ qW16,   _Float16* __restrict__ attA16,
    _Float16* __restrict__ langA16)
{
    const int bid = blockIdx.x, tid = threadIdx.x;
    const float* src; _Float16* dst;
    if (bid < 8192) {                      // attW: 4096 rows x 4096 (3072 Wih | 1024 Whh)
        int i = bid * 256 + tid;
        int row = i / 512, k = (i % 512) * 8;
        src = (k < 3072) ? att_Wih + (size_t)row * 3072 + k
                         : att_Whh + (size_t)row * 1024 + (k - 3072);
        dst = attW16 + ((size_t)(k >> 5) * 4096 + row) * 32 + (k & 31);
    } else if (bid < 18432) {              // langW: 4096 x 5120 (4096 Wih | 1024 Whh)
        int i = (bid - 8192) * 256 + tid;
        int row = i / 640, k = (i % 640) * 8;
        src = (k < 4096) ? lang_Wih + (size_t)row * 4096 + k
                         : lang_Whh + (size_t)row * 1024 + (k - 4096);
        dst = langW16 + ((size_t)(k >> 5) * 4096 + row) * 32 + (k & 31);
    } else if (bid < 19200) {              // qW: 1536 x 1024 (3 x 512 rows)
        int i = (bid - 18432) * 256 + tid;
        int row = i / 128, k = (i % 128) * 8;
        int m = row >> 9;
        const float* Wq = (m == 0) ? attr_Wq : (m == 1) ? obj_Wq : rela_Wq;
        src = Wq + (size_t)(row & 511) * 1024 + k;
        dst = qW16 + ((size_t)(k >> 5) * 1536 + row) * 32 + (k & 31);
    } else if (bid < 21248) {              // attA: 1024 x 4096 (h1|fc|xt|h0)
        int i = (bid - 19200) * 256 + tid;
        int row = i >> 9, k = (i & 511) * 8;
        int seg = k >> 10;
        const float* s = (seg == 0) ? h1 : (seg == 1) ? fc : (seg == 2) ? xt : h0;
        src = s + (size_t)row * 1024 + (k & 1023);
        dst = attA16 + ((size_t)(k >> 5) * 1024 + row) * 32 + (k & 31);
    } else {                               // langA h1 segment: panels 128..159
        int i = (bid - 21248) * 256 + tid;
        int row = i >> 7, k = (i & 127) * 8;
        src = h1 + (size_t)row * 1024 + k;
        dst = langA16 + ((size_t)(128 + (k >> 5)) * 1024 + row) * 32 + (k & 31);
    }
    float4 v0 = reinterpret_cast<const float4*>(src)[0];
    float4 v1 = reinterpret_cast<const float4*>(src)[1];
    *reinterpret_cast<half8*>(dst) = cvt8(v0, v1);
}

// ==================== 128x128 f16 panel GEMM (kept for q-GEMM) ====================
__global__ __launch_bounds__(256) void gemm16(
    const _Float16* __restrict__ A, int RA,
    const _Float16* __restrict__ W, int RW,
    _Float16* __restrict__ Cpart, int ldc, int kLen)
{
    __shared__ _Float16 smA[2][128 * 40];
    __shared__ _Float16 smW[2][128 * 40];
    const int tid  = threadIdx.x;
    const int lane = tid & 63;
    const int wid  = tid >> 6;
    const int wm   = wid >> 1, wn = wid & 1;
    const int m0   = blockIdx.y * 128;
    const int n0   = blockIdx.x * 128;
    const int kb   = blockIdx.z * kLen;
    const int nt   = kLen >> 5;
    const int fr   = lane & 15;
    const int kq   = lane >> 4;
    const int r0   = tid >> 2;
    const int c0   = (tid & 3) * 8;

    f32x4 acc[4][4] = {};
    half8 va0, va1, vw0, vw1;

    auto LOADP = [&](int lk) {
        size_t pa = ((size_t)((kb + lk) >> 5) * RA + m0) * 32 + tid * 8;
        va0 = *reinterpret_cast<const half8*>(A + pa);
        va1 = *reinterpret_cast<const half8*>(A + pa + 2048);
        size_t pw = ((size_t)((kb + lk) >> 5) * RW + n0) * 32 + tid * 8;
        vw0 = *reinterpret_cast<const half8*>(W + pw);
        vw1 = *reinterpret_cast<const half8*>(W + pw + 2048);
    };
    auto WRITE = [&](int buf) {
        *reinterpret_cast<half8*>(&smA[buf][r0 * 40 + c0])        = va0;
        *reinterpret_cast<half8*>(&smA[buf][(r0 + 64) * 40 + c0]) = va1;
        *reinterpret_cast<half8*>(&smW[buf][r0 * 40 + c0])        = vw0;
        *reinterpret_cast<half8*>(&smW[buf][(r0 + 64) * 40 + c0]) = vw1;
    };
    auto DOMFMA = [&](int buf) {
        half8 af[4], bf[4];
        #pragma unroll
        for (int i = 0; i < 4; ++i) {
            af[i] = *reinterpret_cast<const half8*>(&smA[buf][(wm * 64 + i * 16 + fr) * 40 + kq * 8]);
            bf[i] = *reinterpret_cast<const half8*>(&smW[buf][(wn * 64 + i * 16 + fr) * 40 + kq * 8]);
        }
        #pragma unroll
        for (int i = 0; i < 4; ++i)
            #pragma unroll
            for (int j = 0; j < 4; ++j)
                acc[i][j] = __builtin_amdgcn_mfma_f32_16x16x32_f16(af[i], bf[j], acc[i][j], 0, 0, 0);
    };

    LOADP(0); WRITE(0);
    __syncthreads();
    int cur = 0;
    for (int it = 0; it < nt - 1; ++it) {
        LOADP((it + 1) * 32);
        DOMFMA(cur);
        WRITE(cur ^ 1);
        __syncthreads();
        cur ^= 1;
    }
    DOMFMA(cur);

    _Float16* cp = Cpart + (size_t)blockIdx.z * 1024ull * (size_t)ldc;
    #pragma unroll
    for (int j = 0; j < 4; ++j) {
        int nc = n0 + wn * 64 + j * 16 + fr;
        #pragma unroll
        for (int i = 0; i < 4; ++i) {
            int rb = m0 + wm * 64 + i * 16 + kq * 4;
            #pragma unroll
            for (int r = 0; r < 4; ++r)
                cp[(size_t)(rb + r) * ldc + nc] = (_Float16)acc[i][j][r];
        }
    }
}

// ==================== 256x128 f16 panel GEMM (big GEMMs) ====================
__global__ __launch_bounds__(256) void gemm16b(
    const _Float16* __restrict__ A, int RA,
    const _Float16* __restrict__ W, int RW,
    _Float16* __restrict__ Cpart, int ldc, int kLen)
{
    __shared__ _Float16 smA[2][256 * 40];
    __shared__ _Float16 smW[2][128 * 40];
    const int tid  = threadIdx.x;
    const int lane = tid & 63;
    const int wid  = tid >> 6;
    const int wm   = wid >> 1, wn = wid & 1;
    const int m0   = blockIdx.y * 256;
    const int n0   = blockIdx.x * 128;
    const int kb   = blockIdx.z * kLen;
    const int nt   = kLen >> 5;
    const int fr   = lane & 15;
    const int kq   = lane >> 4;
    const int r0   = tid >> 2;            // 0..63
    const int c0   = (tid & 3) * 8;

    f32x4 acc[8][4] = {};
    half8 va0, va1, va2, va3, vw0, vw1;

    auto LOADP = [&](int lk) {
        size_t pa = ((size_t)((kb + lk) >> 5) * RA + m0) * 32 + tid * 8;
        va0 = *reinterpret_cast<const half8*>(A + pa);
        va1 = *reinterpret_cast<const half8*>(A + pa + 2048);
        va2 = *reinterpret_cast<const half8*>(A + pa + 4096);
        va3 = *reinterpret_cast<const half8*>(A + pa + 6144);
        size_t pw = ((size_t)((kb + lk) >> 5) * RW + n0) * 32 + tid * 8;
        vw0 = *reinterpret_cast<const half8*>(W + pw);
        vw1 = *reinterpret_cast<const half8*>(W + pw + 2048);
    };
    auto WRITE = [&](int buf) {
        *reinterpret_cast<half8*>(&smA[buf][r0 * 40 + c0])         = va0;
        *reinterpret_cast<half8*>(&smA[buf][(r0 + 64) * 40 + c0])  = va1;
        *reinterpret_cast<half8*>(&smA[buf][(r0 + 128) * 40 + c0]) = va2;
        *reinterpret_cast<half8*>(&smA[buf][(r0 + 192) * 40 + c0]) = va3;
        *reinterpret_cast<half8*>(&smW[buf][r0 * 40 + c0])         = vw0;
        *reinterpret_cast<half8*>(&smW[buf][(r0 + 64) * 40 + c0])  = vw1;
    };
    auto DOMFMA = [&](int buf) {
        half8 bf[4];
        #pragma unroll
        for (int j = 0; j < 4; ++j)
            bf[j] = *reinterpret_cast<const half8*>(&smW[buf][(wn * 64 + j * 16 + fr) * 40 + kq * 8]);
        #pragma unroll
        for (int i = 0; i < 8; ++i) {
            half8 af = *reinterpret_cast<const half8*>(&smA[buf][(wm * 128 + i * 16 + fr) * 40 + kq * 8]);
            #pragma unroll
            for (int j = 0; j < 4; ++j)
                acc[i][j] = __builtin_amdgcn_mfma_f32_16x16x32_f16(af, bf[j], acc[i][j], 0, 0, 0);
        }
    };

    LOADP(0); WRITE(0);
    __syncthreads();
    int cur = 0;
    for (int it = 0; it < nt - 1; ++it) {
        LOADP((it + 1) * 32);
        DOMFMA(cur);
        WRITE(cur ^ 1);
        __syncthreads();
        cur ^= 1;
    }
    DOMFMA(cur);

    _Float16* cp = Cpart + (size_t)blockIdx.z * 1024ull * (size_t)ldc;
    #pragma unroll
    for (int j = 0; j < 4; ++j) {
        int nc = n0 + wn * 64 + j * 16 + fr;
        #pragma unroll
        for (int i = 0; i < 8; ++i) {
            int rb = m0 + wm * 128 + i * 16 + kq * 4;
            #pragma unroll
            for (int r = 0; r < 4; ++r)
                cp[(size_t)(rb + r) * ldc + nc] = (_Float16)acc[i][j][r];
        }
    }
}

// ==================== attention (persistent grid-stride blocks) ====================
// scores: 2048 blocks x 4 waves grid-stride over 1024*116 (b,row) tasks.
__global__ __launch_bounds__(256, 1) void att_scores(
    const float* __restrict__ p_attr, const float* __restrict__ p_obj,
    const float* __restrict__ p_rela,
    const _Float16* __restrict__ q16,
    const float* __restrict__ attr_bq, const float* __restrict__ obj_bq,
    const float* __restrict__ rela_bq,
    const float* __restrict__ attr_wa, const float* __restrict__ obj_wa,
    const float* __restrict__ rela_wa,
    const float* __restrict__ attr_ba, const float* __restrict__ obj_ba,
    const float* __restrict__ rela_ba,
    float* __restrict__ scg)
{
    const int lane = threadIdx.x & 63;
    const unsigned stride = gridDim.x * 4u;
    for (unsigned gw = blockIdx.x * 4u + (threadIdx.x >> 6); gw < 118784u; gw += stride) {
        const unsigned b = gw / 116u;
        const int r = (int)(gw - b * 116u);
        const float* pf; const float* bq; const float* wa; const float* ba;
        int l, moff, scoff, L;
        if (r < 16)      { pf = p_attr; bq = attr_bq; wa = attr_wa; ba = attr_ba; l = r;      moff = 0;    scoff = 0;  L = 16; }
        else if (r < 52) { pf = p_obj;  bq = obj_bq;  wa = obj_wa;  ba = obj_ba;  l = r - 16; moff = 512;  scoff = 16; L = 36; }
        else             { pf = p_rela; bq = rela_bq; wa = rela_wa; ba = rela_ba; l = r - 52; moff = 1024; scoff = 52; L = 64; }

        const f32x4* pf4 = reinterpret_cast<const f32x4*>(pf) + ((size_t)b * L + l) * 128;
        f32x4 a0 = __builtin_nontemporal_load(pf4 + lane);
        f32x4 a1 = __builtin_nontemporal_load(pf4 + lane + 64);
        const _Float16* qb = q16 + (size_t)b * 1536 + moff;
        half4v hq0a = *reinterpret_cast<const half4v*>(qb + lane * 4);
        half4v hq0b = *reinterpret_cast<const half4v*>(qb + 256 + lane * 4);
        const _Float16* qb1 = qb + 1536ull * 1024;
        half4v hq1a = *reinterpret_cast<const half4v*>(qb1 + lane * 4);
        half4v hq1b = *reinterpret_cast<const half4v*>(qb1 + 256 + lane * 4);
        const f32x4* bq4 = reinterpret_cast<const f32x4*>(bq);
        const f32x4* wa4 = reinterpret_cast<const f32x4*>(wa);
        f32x4 b0 = bq4[lane], b1 = bq4[lane + 64];
        f32x4 w0 = wa4[lane], w1 = wa4[lane + 64];

        float s = tanh_fast(a0[0] + (float)hq0a[0] + (float)hq1a[0] + b0[0]) * w0[0]
                + tanh_fast(a0[1] + (float)hq0a[1] + (float)hq1a[1] + b0[1]) * w0[1]
                + tanh_fast(a0[2] + (float)hq0a[2] + (float)hq1a[2] + b0[2]) * w0[2]
                + tanh_fast(a0[3] + (float)hq0a[3] + (float)hq1a[3] + b0[3]) * w0[3]
                + tanh_fast(a1[0] + (float)hq0b[0] + (float)hq1b[0] + b1[0]) * w1[0]
                + tanh_fast(a1[1] + (float)hq0b[1] + (float)hq1b[1] + b1[1]) * w1[1]
                + tanh_fast(a1[2] + (float)hq0b[2] + (float)hq1b[2] + b1[2]) * w1[2]
                + tanh_fast(a1[3] + (float)hq0b[3] + (float)hq1b[3] + b1[3]) * w1[3];
        #pragma unroll
        for (int off = 32; off >= 1; off >>= 1) s += __shfl_xor(s, off);
        if (lane == 0) scg[(size_t)b * 128 + scoff + l] = s + ba[0];
    }
}

// softmax (wave 0) + weighted sum for one (b, mod, dhalf) unit.
template<int L>
__device__ __forceinline__ void wsum_mod(
    const float* __restrict__ feats, const float* __restrict__ scg_b,
    const float* __restrict__ mask_b,
    float* __restrict__ outa, _Float16* __restrict__ dst16,
    int b, int dhalf, float* wgt)
{
    const int tid = threadIdx.x;   // 0..127
    if (tid < 64) {
        float v = (tid < L) ? scg_b[tid] : -1e30f;
        float m = v;
        #pragma unroll
        for (int off = 32; off >= 1; off >>= 1) m = fmaxf(m, __shfl_xor(m, off));
        float e = (tid < L) ? __expf(v - m) : 0.f;
        float sum = e;
        #pragma unroll
        for (int off = 32; off >= 1; off >>= 1) sum += __shfl_xor(sum, off);
        float w = e / sum;
        float wm = (tid < L) ? w * mask_b[tid] : 0.f;
        float s2 = wm;
        #pragma unroll
        for (int off = 32; off >= 1; off >>= 1) s2 += __shfl_xor(s2, off);
        wgt[tid] = wm / (s2 + 1e-8f);
    }
    __syncthreads();

    const int d0 = dhalf * 512 + tid * 4;
    const f32x4* fp = reinterpret_cast<const f32x4*>(feats + (size_t)b * L * 1024 + d0);
    f32x4 acc0 = {0.f, 0.f, 0.f, 0.f};
    f32x4 acc1 = {0.f, 0.f, 0.f, 0.f};
    constexpr int NFULL = L / 8;
    #pragma unroll
    for (int g = 0; g < NFULL; ++g) {
        f32x4 v0 = __builtin_nontemporal_load(fp + (size_t)(g * 8 + 0) * 256);
        f32x4 v1 = __builtin_nontemporal_load(fp + (size_t)(g * 8 + 1) * 256);
        f32x4 v2 = __builtin_nontemporal_load(fp + (size_t)(g * 8 + 2) * 256);
        f32x4 v3 = __builtin_nontemporal_load(fp + (size_t)(g * 8 + 3) * 256);
        f32x4 v4 = __builtin_nontemporal_load(fp + (size_t)(g * 8 + 4) * 256);
        f32x4 v5 = __builtin_nontemporal_load(fp + (size_t)(g * 8 + 5) * 256);
        f32x4 v6 = __builtin_nontemporal_load(fp + (size_t)(g * 8 + 6) * 256);
        f32x4 v7 = __builtin_nontemporal_load(fp + (size_t)(g * 8 + 7) * 256);
        float w0 = wgt[g * 8 + 0], w1 = wgt[g * 8 + 1], w2 = wgt[g * 8 + 2], w3 = wgt[g * 8 + 3];
        float w4 = wgt[g * 8 + 4], w5 = wgt[g * 8 + 5], w6 = wgt[g * 8 + 6], w7 = wgt[g * 8 + 7];
        acc0 += w0 * v0 + w2 * v2 + w4 * v4 + w6 * v6;
        acc1 += w1 * v1 + w3 * v3 + w5 * v5 + w7 * v7;
    }
    #pragma unroll
    for (int lg = NFULL * 8; lg < L; lg += 2) {
        f32x4 v0 = __builtin_nontemporal_load(fp + (size_t)lg * 256);
        f32x4 v1 = __builtin_nontemporal_load(fp + (size_t)(lg + 1) * 256);
        acc0 += wgt[lg] * v0;
        acc1 += wgt[lg + 1] * v1;
    }
    f32x4 o = acc0 + acc1;
    if (dst16) {   // panel layout: [(d0>>5)][1024][32]
        half4v h = { f2h(o[0]), f2h(o[1]), f2h(o[2]), f2h(o[3]) };
        *reinterpret_cast<half4v*>(dst16 + ((size_t)(d0 >> 5) * 1024 + b) * 32 + (d0 & 31)) = h;
    }
    if (outa)
        *reinterpret_cast<f32x4*>(outa + (size_t)b * 1024 + d0) = o;
}

// persistent: 2048 blocks x 128 grid-stride over 6144 units
// unit space: [0,2048)=rela, [2048,4096)=obj, [4096,6144)=attr.
__global__ __launch_bounds__(128, 1) void att_wsum(
    const float* __restrict__ attr_feats, const float* __restrict__ obj_feats,
    const float* __restrict__ rela_feats,
    const float* __restrict__ attr_masks, const float* __restrict__ att_masks,
    const float* __restrict__ rela_masks,
    const float* __restrict__ scg,
    float* __restrict__ a32,
    _Float16* __restrict__ langA16)
{
    __shared__ float wgt[64];
    for (int unit = blockIdx.x; unit < 6144; unit += gridDim.x) {
        const int sub = unit >> 11;
        const int b   = (unit & 2047) >> 1;
        const int dh  = unit & 1;
        if (sub == 0)
            wsum_mod<64>(rela_feats, scg + (size_t)b * 128 + 52, rela_masks + (size_t)b * 64,
                         a32 ? a32 + 2ull * 1024 * 1024 : nullptr,
                         langA16 ? langA16 + 96ull * 1024 * 32 : nullptr, b, dh, wgt);
        else if (sub == 1)
            wsum_mod<36>(obj_feats,  scg + (size_t)b * 128 + 16, att_masks + (size_t)b * 36,
                         a32 ? a32 + 1ull * 1024 * 1024 : nullptr,
                         langA16 ? langA16 + 64ull * 1024 * 32 : nullptr, b, dh, wgt);
        else
            wsum_mod<16>(attr_feats, scg + (size_t)b * 128 + 0,  attr_masks + (size_t)b * 16,
                         a32, langA16 ? langA16 + 32ull * 1024 * 32 : nullptr, b, dh, wgt);
        __syncthreads();   // wgt reuse across units
    }
}

// LSTM elementwise; optional f16 panel output.
__global__ __launch_bounds__(256) void lstm4(
    const _Float16* __restrict__ g, size_t zstride, int nz,
    const float* __restrict__ bih, const float* __restrict__ bhh,
    const float* __restrict__ c_prev,
    float* __restrict__ hA, float* __restrict__ hB,
    _Float16* __restrict__ h16,
    float* __restrict__ c_out)
{
    int idx = blockIdx.x * 256 + threadIdx.x;
    int b = idx >> 10, r = idx & 1023;
    size_t base = (size_t)b * 4096;
    float gi = bih[r]        + bhh[r];
    float gf = bih[1024 + r] + bhh[1024 + r];
    float gg = bih[2048 + r] + bhh[2048 + r];
    float go = bih[3072 + r] + bhh[3072 + r];
    for (int z = 0; z < nz; ++z) {
        const _Float16* gz = g + (size_t)z * zstride + base;
        gi += (float)gz[r];
        gf += (float)gz[1024 + r];
        gg += (float)gz[2048 + r];
        go += (float)gz[3072 + r];
    }
    float si = 1.f / (1.f + __expf(-gi));
    float sf = 1.f / (1.f + __expf(-gf));
    float so = 1.f / (1.f + __expf(-go));
    float c2 = sf * c_prev[idx] + si * tanh_fast(gg);
    float h2 = so * tanh_fast(c2);
    hA[idx] = h2;
    if (hB) hB[idx] = h2;
    if (h16) h16[((size_t)(r >> 5) * 1024 + b) * 32 + (r & 31)] = (_Float16)h2;
    c_out[idx] = c2;
}

// ==================== fallback f32-source GEMM (R11) ====================
#define LDSB (128 * 40)
__device__ __forceinline__ void gemm_body(
    _Float16* __restrict__ sm,
    const float* A0, const float* A1, const float* A2p, const float* A3,
    const float* A4,
    const float* W0, const float* W1, const float* W2,
    int w0cols, int w0s, int w1s, int nsel,
    _Float16* __restrict__ Cpart, int ldc,
    int kb, int kLen, int ntile, int mtile, int zout)
{
    _Float16* smA = sm;
    _Float16* smW = sm + 2 * LDSB;
    const int tid  = threadIdx.x;
    const int lane = tid & 63;
    const int wid  = tid >> 6;
    const int wm   = wid >> 1, wn = wid & 1;
    const int m0   = mtile * 128;
    const int n0   = ntile * 128;
    const int nt   = kLen >> 5;
    const int srow = tid >> 3;
    const int scol = (tid & 7) << 2;
    const int fr   = lane & 15;
    const int kq   = lane >> 4;

    const float* wsel = nullptr;
    if (nsel) {
        int sel = n0 >> 9;
        const float* Wq = (sel == 0) ? W0 : (sel == 1) ? W1 : W2;
        wsel = Wq + (size_t)((n0 & 511) + srow) * 1024 + kb + scol;
    }
    f32x4 acc[4][4] = {};
    float4 va[4], vw[4];
    auto LOADA = [&](int lk) {
        int gk = kb + lk;
        int seg = gk >> 10;
        const float* ap = (seg == 0) ? A0 : (seg == 1) ? A1 : (seg == 2) ? A2p
                        : (seg == 3) ? A3 : A4;
        ap += (size_t)(m0 + srow) * 1024 + (gk & 1023) + scol;
        #pragma unroll
        for (int p = 0; p < 4; ++p)
            va[p] = *reinterpret_cast<const float4*>(ap + (size_t)p * 32 * 1024);
    };
    auto LOADW = [&](int lk) {
        const float* wp; int wstr;
        if (nsel) { wp = wsel + lk; wstr = 1024; }
        else {
            int gk = kb + lk;
            if (gk < w0cols) { wp = W0 + (size_t)(n0 + srow) * w0s + gk + scol;            wstr = w0s; }
            else             { wp = W1 + (size_t)(n0 + srow) * w1s + (gk - w0cols) + scol; wstr = w1s; }
        }
        #pragma unroll
        for (int p = 0; p < 4; ++p)
            vw[p] = *reinterpret_cast<const float4*>(wp + (size_t)p * 32 * wstr);
    };
    auto WRITEA = [&](int buf) {
        _Float16* d = smA + buf * LDSB;
        #pragma unroll
        for (int p = 0; p < 4; ++p) {
            half4v h = { f2h(va[p].x), f2h(va[p].y), f2h(va[p].z), f2h(va[p].w) };
            *reinterpret_cast<half4v*>(&d[(srow + p * 32) * 40 + scol]) = h;
        }
    };
    auto WRITEW = [&](int buf) {
        _Float16* d = smW + buf * LDSB;
        #pragma unroll
        for (int p = 0; p < 4; ++p) {
            half4v h = { f2h(vw[p].x), f2h(vw[p].y), f2h(vw[p].z), f2h(vw[p].w) };
            *reinterpret_cast<half4v*>(&d[(srow + p * 32) * 40 + scol]) = h;
        }
    };
    auto DOMFMA = [&](int buf) {
        half8 af[4], bf[4];
        _Float16* sA = smA + buf * LDSB;
        _Float16* sW = smW + buf * LDSB;
        #pragma unroll
        for (int i = 0; i < 4; ++i) {
            af[i] = *reinterpret_cast<const half8*>(&sA[(wm * 64 + i * 16 + fr) * 40 + kq * 8]);
            bf[i] = *reinterpret_cast<const half8*>(&sW[(wn * 64 + i * 16 + fr) * 40 + kq * 8]);
        }
        #pragma unroll
        for (int i = 0; i < 4; ++i)
            #pragma unroll
            for (int j = 0; j < 4; ++j)
                acc[i][j] = __builtin_amdgcn_mfma_f32_16x16x32_f16(af[i], bf[j], acc[i][j], 0, 0, 0);
    };
    LOADA(0); LOADW(0);
    WRITEA(0); WRITEW(0);
    __syncthreads();
    int cur = 0;
    for (int it = 0; it < nt - 1; ++it) {
        LOADA((it + 1) * 32);
        LOADW((it + 1) * 32);
        DOMFMA(cur);
        WRITEA(cur ^ 1);
        WRITEW(cur ^ 1);
        __syncthreads();
        cur ^= 1;
    }
    DOMFMA(cur);
    _Float16* cp = Cpart + (size_t)zout * 1024ull * (size_t)ldc;
    #pragma unroll
    for (int j = 0; j < 4; ++j) {
        int nc = n0 + wn * 64 + j * 16 + fr;
        #pragma unroll
        for (int i = 0; i < 4; ++i) {
            int rb = m0 + wm * 64 + i * 16 + kq * 4;
            #pragma unroll
            for (int r = 0; r < 4; ++r)
                cp[(size_t)(rb + r) * ldc + nc] = (_Float16)acc[i][j][r];
        }
    }
}

__global__ __launch_bounds__(256) void gemm_hf(
    const float* A0, const float* A1, const float* A2p, const float* A3,
    const float* A4,
    const float* W0, const float* W1, const float* W2,
    int w0cols, int w0s, int w1s, int nsel,
    _Float16* Cpart, int ldc, int kLen, int zbase)
{
    __shared__ _Float16 sm[4 * LDSB];
    gemm_body(sm, A0, A1, A2p, A3, A4, W0, W1, W2, w0cols, w0s, w1s, nsel,
              Cpart, ldc, blockIdx.z * kLen, kLen,
              blockIdx.x, blockIdx.y, zbase + blockIdx.z);
}

extern "C" void kernel_launch(void* const* d_in, const int* in_sizes, int n_in,
                              void* d_out, int out_size, void* d_ws, size_t ws_size,
                              hipStream_t stream)
{
    const size_t BR = 1024ull * 1024ull;
    const float* xt         = (const float*)d_in[0];
    const float* fc         = (const float*)d_in[1];
    const float* state_h    = (const float*)d_in[2];
    const float* state_c    = (const float*)d_in[3];
    const float* attr_feats = (const float*)d_in[4];
    const float* obj_feats  = (const float*)d_in[5];
    const float* rela_feats = (const float*)d_in[6];
    const float* p_attr     = (const float*)d_in[7];
    const float* p_obj      = (const float*)d_in[8];
    const float* p_rela     = (const float*)d_in[9];
    const float* attr_masks = (const float*)d_in[10];
    const float* att_masks  = (const float*)d_in[11];
    const float* rela_masks = (const float*)d_in[12];
    const float* att_Wih    = (const float*)d_in[13];
    const float* att_Whh    = (const float*)d_in[14];
    const float* att_bih    = (const float*)d_in[15];
    const float* att_bhh    = (const float*)d_in[16];
    const float* lang_Wih   = (const float*)d_in[17];
    const float* lang_Whh   = (const float*)d_in[18];
    const float* lang_bih   = (const float*)d_in[19];
    const float* lang_bhh   = (const float*)d_in[20];
    const float* attr_Wq    = (const float*)d_in[21];
    const float* attr_bq    = (const float*)d_in[22];
    const float* attr_wa    = (const float*)d_in[23];
    const float* attr_ba    = (const float*)d_in[24];
    const float* obj_Wq     = (const float*)d_in[25];
    const float* obj_bq     = (const float*)d_in[26];
    const float* obj_wa     = (const float*)d_in[27];
    const float* obj_ba     = (const float*)d_in[28];
    const float* rela_Wq    = (const float*)d_in[29];
    const float* rela_bq    = (const float*)d_in[30];
    const float* rela_wa    = (const float*)d_in[31];
    const float* rela_ba    = (const float*)d_in[32];

    float* out = (float*)d_out;
    const float* h0 = state_h;
    const float* h1 = state_h + BR;
    float* h_att = out + BR;
    float* scg  = out;   // scratch in out slot 0 (fully rewritten by final lstm4)

    dim3 blk(256);

    // -------- pre-mode: f16 panel-packed operands (needs 131 MiB ws) --------
    const bool pre = ws_size >= 137363456ull;
    if (pre) {
        _Float16* g16     = (_Float16*)d_ws;                  // 16M f16
        _Float16* q16     = g16     + 16ull * BR;             // 3M
        _Float16* attW16  = q16     + 3ull  * BR;             // 16M
        _Float16* langW16 = attW16  + 16ull * BR;             // 20M
        _Float16* qW16    = langW16 + 20ull * BR;             // 1.5M
        _Float16* attA16  = qW16    + 1536ull * 1024;         // 4M
        _Float16* langA16 = attA16  + 4ull  * BR;             // 5M

        pack_all<<<dim3(21760), blk, 0, stream>>>(
            att_Wih, att_Whh, lang_Wih, lang_Whh,
            attr_Wq, obj_Wq, rela_Wq,
            h1, fc, xt, h0,
            attW16, langW16, qW16, attA16, langA16);
        gemm16b<<<dim3(32, 4, 4), blk, 0, stream>>>(
            attA16, 1024, attW16, 4096, g16, 4096, 1024);
        lstm4<<<dim3(4096), blk, 0, stream>>>(
            g16, 4ull * BR, 4, att_bih, att_bhh, state_c,
            h_att, nullptr, langA16, out + 3 * BR);
        gemm16<<<dim3(12, 8, 2), blk, 0, stream>>>(
            langA16, 1024, qW16, 1536, q16, 1536, 512);
        att_scores<<<dim3(2048), blk, 0, stream>>>(
            p_attr, p_obj, p_rela, q16,
            attr_bq, obj_bq, rela_bq, attr_wa, obj_wa, rela_wa,
            attr_ba, obj_ba, rela_ba, scg);
        att_wsum<<<dim3(2048), dim3(128), 0, stream>>>(
            attr_feats, obj_feats, rela_feats,
            attr_masks, att_masks, rela_masks, scg, nullptr, langA16);
        gemm16b<<<dim3(32, 4, 4), blk, 0, stream>>>(
            langA16, 1024, langW16, 4096, g16, 4096, 1280);
        lstm4<<<dim3(4096), blk, 0, stream>>>(
            g16, 4ull * BR, 4, lang_bih, lang_bhh, state_c + BR,
            out, out + 2 * BR, nullptr, out + 4 * BR);
        return;
    }

    // -------- fallback: R11 path --------
    const bool big = ws_size >= 52428800ull;
    const int gslots = big ? 4 : 2;
    _Float16* g16 = (_Float16*)d_ws;
    _Float16* q16 = g16 + (size_t)gslots * 4ull * BR;
    float*    a32 = (float*)(q16 + 2ull * 1536 * 1024);
    float* a_attr = a32;
    float* a_obj  = a32 + BR;
    float* a_rela = a32 + 2 * BR;
    const int zsplit = big ? 4 : 2;

    gemm_hf<<<dim3(32, 8, zsplit), blk, 0, stream>>>(
        h1, fc, xt, h0, h0, att_Wih, att_Whh, att_Whh,
        3072, 3072, 1024, 0, g16, 4096, 4096 / zsplit, 0);
    lstm4<<<dim3(4096), blk, 0, stream>>>(
        g16, 4ull * BR, gslots, att_bih, att_bhh, state_c,
        h_att, nullptr, nullptr, out + 3 * BR);
    gemm_hf<<<dim3(12, 8, 2), blk, 0, stream>>>(
        h_att, h_att, h_att, h_att, h_att,
        attr_Wq, obj_Wq, rela_Wq, 0, 1024, 1024, 1,
        q16, 1536, 512, 0);
    att_scores<<<dim3(2048), blk, 0, stream>>>(
        p_attr, p_obj, p_rela, q16,
        attr_bq, obj_bq, rela_bq, attr_wa, obj_wa, rela_wa,
        attr_ba, obj_ba, rela_ba, scg);
    att_wsum<<<dim3(2048), dim3(128), 0, stream>>>(
        attr_feats, obj_feats, rela_feats,
        attr_masks, att_masks, rela_masks, scg, a32, nullptr);
    gemm_hf<<<dim3(32, 8, zsplit), blk, 0, stream>>>(
        h_att, a_attr, a_obj, a_rela, h1,
        lang_Wih, lang_Whh, lang_Whh, 4096, 4096, 1024, 0,
        g16, 4096, 5120 / zsplit, 0);
    lstm4<<<dim3(4096), blk, 0, stream>>>(
        g16, 4ull * BR, gslots, lang_bih, lang_bhh, state_c + BR,
        out, out + 2 * BR, nullptr, out + 4 * BR);
}

// Round 18
// 363.701 us; speedup vs baseline: 1.0414x; 1.0414x over previous
//
#include <hip/hip_runtime.h>
#include <math.h>

typedef _Float16 half8  __attribute__((ext_vector_type(8)));
typedef _Float16 half4v __attribute__((ext_vector_type(4)));
typedef float    f32x4  __attribute__((ext_vector_type(4)));

__device__ __forceinline__ _Float16 f2h(float f) { return (_Float16)f; }

__device__ __forceinline__ float tanh_fast(float x) {
    float e = __expf(2.f * x);
    return 1.f - 2.f / (e + 1.f);
}

__device__ __forceinline__ half8 cvt8(float4 a, float4 b) {
    half8 h = { f2h(a.x), f2h(a.y), f2h(a.z), f2h(a.w),
                f2h(b.x), f2h(b.y), f2h(b.z), f2h(b.w) };
    return h;
}

// ==================== pack: f32 -> f16, panel layout [K/32][rows][32] ====================
__global__ __launch_bounds__(256) void pack_all(
    const float* __restrict__ att_Wih,  const float* __restrict__ att_Whh,
    const float* __restrict__ lang_Wih, const float* __restrict__ lang_Whh,
    const float* __restrict__ attr_Wq,  const float* __restrict__ obj_Wq,
    const float* __restrict__ rela_Wq,
    const float* __restrict__ h1, const float* __restrict__ fc,
    const float* __restrict__ xt, const float* __restrict__ h0,
    _Float16* __restrict__ attW16, _Float16* __restrict__ langW16,
    _Float16* __restrict__ qW16,   _Float16* __restrict__ attA16,
    _Float16* __restrict__ langA16)
{
    const int bid = blockIdx.x, tid = threadIdx.x;
    const float* src; _Float16* dst;
    if (bid < 8192) {                      // attW: 4096 rows x 4096 (3072 Wih | 1024 Whh)
        int i = bid * 256 + tid;
        int row = i / 512, k = (i % 512) * 8;
        src = (k < 3072) ? att_Wih + (size_t)row * 3072 + k
                         : att_Whh + (size_t)row * 1024 + (k - 3072);
        dst = attW16 + ((size_t)(k >> 5) * 4096 + row) * 32 + (k & 31);
    } else if (bid < 18432) {              // langW: 4096 x 5120 (4096 Wih | 1024 Whh)
        int i = (bid - 8192) * 256 + tid;
        int row = i / 640, k = (i % 640) * 8;
        src = (k < 4096) ? lang_Wih + (size_t)row * 4096 + k
                         : lang_Whh + (size_t)row * 1024 + (k - 4096);
        dst = langW16 + ((size_t)(k >> 5) * 4096 + row) * 32 + (k & 31);
    } else if (bid < 19200) {              // qW: 1536 x 1024 (3 x 512 rows)
        int i = (bid - 18432) * 256 + tid;
        int row = i / 128, k = (i % 128) * 8;
        int m = row >> 9;
        const float* Wq = (m == 0) ? attr_Wq : (m == 1) ? obj_Wq : rela_Wq;
        src = Wq + (size_t)(row & 511) * 1024 + k;
        dst = qW16 + ((size_t)(k >> 5) * 1536 + row) * 32 + (k & 31);
    } else if (bid < 21248) {              // attA: 1024 x 4096 (h1|fc|xt|h0)
        int i = (bid - 19200) * 256 + tid;
        int row = i >> 9, k = (i & 511) * 8;
        int seg = k >> 10;
        const float* s = (seg == 0) ? h1 : (seg == 1) ? fc : (seg == 2) ? xt : h0;
        src = s + (size_t)row * 1024 + (k & 1023);
        dst = attA16 + ((size_t)(k >> 5) * 1024 + row) * 32 + (k & 31);
    } else {                               // langA h1 segment: panels 128..159
        int i = (bid - 21248) * 256 + tid;
        int row = i >> 7, k = (i & 127) * 8;
        src = h1 + (size_t)row * 1024 + k;
        dst = langA16 + ((size_t)(128 + (k >> 5)) * 1024 + row) * 32 + (k & 31);
    }
    float4 v0 = reinterpret_cast<const float4*>(src)[0];
    float4 v1 = reinterpret_cast<const float4*>(src)[1];
    *reinterpret_cast<half8*>(dst) = cvt8(v0, v1);
}

// ==================== 128x128 f16 panel GEMM (kept for q-GEMM) ====================
__global__ __launch_bounds__(256) void gemm16(
    const _Float16* __restrict__ A, int RA,
    const _Float16* __restrict__ W, int RW,
    _Float16* __restrict__ Cpart, int ldc, int kLen)
{
    __shared__ _Float16 smA[2][128 * 40];
    __shared__ _Float16 smW[2][128 * 40];
    const int tid  = threadIdx.x;
    const int lane = tid & 63;
    const int wid  = tid >> 6;
    const int wm   = wid >> 1, wn = wid & 1;
    const int m0   = blockIdx.y * 128;
    const int n0   = blockIdx.x * 128;
    const int kb   = blockIdx.z * kLen;
    const int nt   = kLen >> 5;
    const int fr   = lane & 15;
    const int kq   = lane >> 4;
    const int r0   = tid >> 2;
    const int c0   = (tid & 3) * 8;

    f32x4 acc[4][4] = {};
    half8 va0, va1, vw0, vw1;

    auto LOADP = [&](int lk) {
        size_t pa = ((size_t)((kb + lk) >> 5) * RA + m0) * 32 + tid * 8;
        va0 = *reinterpret_cast<const half8*>(A + pa);
        va1 = *reinterpret_cast<const half8*>(A + pa + 2048);
        size_t pw = ((size_t)((kb + lk) >> 5) * RW + n0) * 32 + tid * 8;
        vw0 = *reinterpret_cast<const half8*>(W + pw);
        vw1 = *reinterpret_cast<const half8*>(W + pw + 2048);
    };
    auto WRITE = [&](int buf) {
        *reinterpret_cast<half8*>(&smA[buf][r0 * 40 + c0])        = va0;
        *reinterpret_cast<half8*>(&smA[buf][(r0 + 64) * 40 + c0]) = va1;
        *reinterpret_cast<half8*>(&smW[buf][r0 * 40 + c0])        = vw0;
        *reinterpret_cast<half8*>(&smW[buf][(r0 + 64) * 40 + c0]) = vw1;
    };
    auto DOMFMA = [&](int buf) {
        half8 af[4], bf[4];
        #pragma unroll
        for (int i = 0; i < 4; ++i) {
            af[i] = *reinterpret_cast<const half8*>(&smA[buf][(wm * 64 + i * 16 + fr) * 40 + kq * 8]);
            bf[i] = *reinterpret_cast<const half8*>(&smW[buf][(wn * 64 + i * 16 + fr) * 40 + kq * 8]);
        }
        #pragma unroll
        for (int i = 0; i < 4; ++i)
            #pragma unroll
            for (int j = 0; j < 4; ++j)
                acc[i][j] = __builtin_amdgcn_mfma_f32_16x16x32_f16(af[i], bf[j], acc[i][j], 0, 0, 0);
    };

    LOADP(0); WRITE(0);
    __syncthreads();
    int cur = 0;
    for (int it = 0; it < nt - 1; ++it) {
        LOADP((it + 1) * 32);
        DOMFMA(cur);
        WRITE(cur ^ 1);
        __syncthreads();
        cur ^= 1;
    }
    DOMFMA(cur);

    _Float16* cp = Cpart + (size_t)blockIdx.z * 1024ull * (size_t)ldc;
    #pragma unroll
    for (int j = 0; j < 4; ++j) {
        int nc = n0 + wn * 64 + j * 16 + fr;
        #pragma unroll
        for (int i = 0; i < 4; ++i) {
            int rb = m0 + wm * 64 + i * 16 + kq * 4;
            #pragma unroll
            for (int r = 0; r < 4; ++r)
                cp[(size_t)(rb + r) * ldc + nc] = (_Float16)acc[i][j][r];
        }
    }
}

// ==================== 256x128 f16 panel GEMM (big GEMMs) ====================
__global__ __launch_bounds__(256) void gemm16b(
    const _Float16* __restrict__ A, int RA,
    const _Float16* __restrict__ W, int RW,
    _Float16* __restrict__ Cpart, int ldc, int kLen)
{
    __shared__ _Float16 smA[2][256 * 40];
    __shared__ _Float16 smW[2][128 * 40];
    const int tid  = threadIdx.x;
    const int lane = tid & 63;
    const int wid  = tid >> 6;
    const int wm   = wid >> 1, wn = wid & 1;
    const int m0   = blockIdx.y * 256;
    const int n0   = blockIdx.x * 128;
    const int kb   = blockIdx.z * kLen;
    const int nt   = kLen >> 5;
    const int fr   = lane & 15;
    const int kq   = lane >> 4;
    const int r0   = tid >> 2;            // 0..63
    const int c0   = (tid & 3) * 8;

    f32x4 acc[8][4] = {};
    half8 va0, va1, va2, va3, vw0, vw1;

    auto LOADP = [&](int lk) {
        size_t pa = ((size_t)((kb + lk) >> 5) * RA + m0) * 32 + tid * 8;
        va0 = *reinterpret_cast<const half8*>(A + pa);
        va1 = *reinterpret_cast<const half8*>(A + pa + 2048);
        va2 = *reinterpret_cast<const half8*>(A + pa + 4096);
        va3 = *reinterpret_cast<const half8*>(A + pa + 6144);
        size_t pw = ((size_t)((kb + lk) >> 5) * RW + n0) * 32 + tid * 8;
        vw0 = *reinterpret_cast<const half8*>(W + pw);
        vw1 = *reinterpret_cast<const half8*>(W + pw + 2048);
    };
    auto WRITE = [&](int buf) {
        *reinterpret_cast<half8*>(&smA[buf][r0 * 40 + c0])         = va0;
        *reinterpret_cast<half8*>(&smA[buf][(r0 + 64) * 40 + c0])  = va1;
        *reinterpret_cast<half8*>(&smA[buf][(r0 + 128) * 40 + c0]) = va2;
        *reinterpret_cast<half8*>(&smA[buf][(r0 + 192) * 40 + c0]) = va3;
        *reinterpret_cast<half8*>(&smW[buf][r0 * 40 + c0])         = vw0;
        *reinterpret_cast<half8*>(&smW[buf][(r0 + 64) * 40 + c0])  = vw1;
    };
    auto DOMFMA = [&](int buf) {
        half8 bf[4];
        #pragma unroll
        for (int j = 0; j < 4; ++j)
            bf[j] = *reinterpret_cast<const half8*>(&smW[buf][(wn * 64 + j * 16 + fr) * 40 + kq * 8]);
        #pragma unroll
        for (int i = 0; i < 8; ++i) {
            half8 af = *reinterpret_cast<const half8*>(&smA[buf][(wm * 128 + i * 16 + fr) * 40 + kq * 8]);
            #pragma unroll
            for (int j = 0; j < 4; ++j)
                acc[i][j] = __builtin_amdgcn_mfma_f32_16x16x32_f16(af, bf[j], acc[i][j], 0, 0, 0);
        }
    };

    LOADP(0); WRITE(0);
    __syncthreads();
    int cur = 0;
    for (int it = 0; it < nt - 1; ++it) {
        LOADP((it + 1) * 32);
        DOMFMA(cur);
        WRITE(cur ^ 1);
        __syncthreads();
        cur ^= 1;
    }
    DOMFMA(cur);

    _Float16* cp = Cpart + (size_t)blockIdx.z * 1024ull * (size_t)ldc;
    #pragma unroll
    for (int j = 0; j < 4; ++j) {
        int nc = n0 + wn * 64 + j * 16 + fr;
        #pragma unroll
        for (int i = 0; i < 8; ++i) {
            int rb = m0 + wm * 128 + i * 16 + kq * 4;
            #pragma unroll
            for (int r = 0; r < 4; ++r)
                cp[(size_t)(rb + r) * ldc + nc] = (_Float16)acc[i][j][r];
        }
    }
}

// ==================== attention ====================
__global__ __launch_bounds__(256, 1) void att_scores(
    const float* __restrict__ p_attr, const float* __restrict__ p_obj,
    const float* __restrict__ p_rela,
    const _Float16* __restrict__ q16,
    const float* __restrict__ attr_bq, const float* __restrict__ obj_bq,
    const float* __restrict__ rela_bq,
    const float* __restrict__ attr_wa, const float* __restrict__ obj_wa,
    const float* __restrict__ rela_wa,
    const float* __restrict__ attr_ba, const float* __restrict__ obj_ba,
    const float* __restrict__ rela_ba,
    float* __restrict__ scg)
{
    const unsigned gw = blockIdx.x * 4u + (threadIdx.x >> 6);
    const int lane = threadIdx.x & 63;
    const unsigned b = gw / 116u;
    const int r = (int)(gw - b * 116u);
    const float* pf; const float* bq; const float* wa; const float* ba;
    int l, moff, scoff, L;
    if (r < 16)      { pf = p_attr; bq = attr_bq; wa = attr_wa; ba = attr_ba; l = r;      moff = 0;    scoff = 0;  L = 16; }
    else if (r < 52) { pf = p_obj;  bq = obj_bq;  wa = obj_wa;  ba = obj_ba;  l = r - 16; moff = 512;  scoff = 16; L = 36; }
    else             { pf = p_rela; bq = rela_bq; wa = rela_wa; ba = rela_ba; l = r - 52; moff = 1024; scoff = 52; L = 64; }

    const f32x4* pf4 = reinterpret_cast<const f32x4*>(pf) + ((size_t)b * L + l) * 128;
    f32x4 a0 = __builtin_nontemporal_load(pf4 + lane);
    f32x4 a1 = __builtin_nontemporal_load(pf4 + lane + 64);
    const _Float16* qb = q16 + (size_t)b * 1536 + moff;
    half4v hq0a = *reinterpret_cast<const half4v*>(qb + lane * 4);
    half4v hq0b = *reinterpret_cast<const half4v*>(qb + 256 + lane * 4);
    const _Float16* qb1 = qb + 1536ull * 1024;
    half4v hq1a = *reinterpret_cast<const half4v*>(qb1 + lane * 4);
    half4v hq1b = *reinterpret_cast<const half4v*>(qb1 + 256 + lane * 4);
    const f32x4* bq4 = reinterpret_cast<const f32x4*>(bq);
    const f32x4* wa4 = reinterpret_cast<const f32x4*>(wa);
    f32x4 b0 = bq4[lane], b1 = bq4[lane + 64];
    f32x4 w0 = wa4[lane], w1 = wa4[lane + 64];

    float s = tanh_fast(a0[0] + (float)hq0a[0] + (float)hq1a[0] + b0[0]) * w0[0]
            + tanh_fast(a0[1] + (float)hq0a[1] + (float)hq1a[1] + b0[1]) * w0[1]
            + tanh_fast(a0[2] + (float)hq0a[2] + (float)hq1a[2] + b0[2]) * w0[2]
            + tanh_fast(a0[3] + (float)hq0a[3] + (float)hq1a[3] + b0[3]) * w0[3]
            + tanh_fast(a1[0] + (float)hq0b[0] + (float)hq1b[0] + b1[0]) * w1[0]
            + tanh_fast(a1[1] + (float)hq0b[1] + (float)hq1b[1] + b1[1]) * w1[1]
            + tanh_fast(a1[2] + (float)hq0b[2] + (float)hq1b[2] + b1[2]) * w1[2]
            + tanh_fast(a1[3] + (float)hq0b[3] + (float)hq1b[3] + b1[3]) * w1[3];
    #pragma unroll
    for (int off = 32; off >= 1; off >>= 1) s += __shfl_xor(s, off);
    if (lane == 0) scg[(size_t)b * 128 + scoff + l] = s + ba[0];
}

// softmax (wave 0) + weighted sum; f16 panel output and/or f32 output.
template<int L>
__device__ __forceinline__ void wsum_mod(
    const float* __restrict__ feats, const float* __restrict__ scg_b,
    const float* __restrict__ mask_b,
    float* __restrict__ outa, _Float16* __restrict__ dst16,
    int b, int dhalf, float* wgt)
{
    const int tid = threadIdx.x;   // 0..127
    if (tid < 64) {
        float v = (tid < L) ? scg_b[tid] : -1e30f;
        float m = v;
        #pragma unroll
        for (int off = 32; off >= 1; off >>= 1) m = fmaxf(m, __shfl_xor(m, off));
        float e = (tid < L) ? __expf(v - m) : 0.f;
        float sum = e;
        #pragma unroll
        for (int off = 32; off >= 1; off >>= 1) sum += __shfl_xor(sum, off);
        float w = e / sum;
        float wm = (tid < L) ? w * mask_b[tid] : 0.f;
        float s2 = wm;
        #pragma unroll
        for (int off = 32; off >= 1; off >>= 1) s2 += __shfl_xor(s2, off);
        wgt[tid] = wm / (s2 + 1e-8f);
    }
    __syncthreads();

    const int d0 = dhalf * 512 + tid * 4;
    const f32x4* fp = reinterpret_cast<const f32x4*>(feats + (size_t)b * L * 1024 + d0);
    f32x4 acc0 = {0.f, 0.f, 0.f, 0.f};
    f32x4 acc1 = {0.f, 0.f, 0.f, 0.f};
    constexpr int NFULL = L / 8;
    #pragma unroll
    for (int g = 0; g < NFULL; ++g) {
        f32x4 v0 = __builtin_nontemporal_load(fp + (size_t)(g * 8 + 0) * 256);
        f32x4 v1 = __builtin_nontemporal_load(fp + (size_t)(g * 8 + 1) * 256);
        f32x4 v2 = __builtin_nontemporal_load(fp + (size_t)(g * 8 + 2) * 256);
        f32x4 v3 = __builtin_nontemporal_load(fp + (size_t)(g * 8 + 3) * 256);
        f32x4 v4 = __builtin_nontemporal_load(fp + (size_t)(g * 8 + 4) * 256);
        f32x4 v5 = __builtin_nontemporal_load(fp + (size_t)(g * 8 + 5) * 256);
        f32x4 v6 = __builtin_nontemporal_load(fp + (size_t)(g * 8 + 6) * 256);
        f32x4 v7 = __builtin_nontemporal_load(fp + (size_t)(g * 8 + 7) * 256);
        float w0 = wgt[g * 8 + 0], w1 = wgt[g * 8 + 1], w2 = wgt[g * 8 + 2], w3 = wgt[g * 8 + 3];
        float w4 = wgt[g * 8 + 4], w5 = wgt[g * 8 + 5], w6 = wgt[g * 8 + 6], w7 = wgt[g * 8 + 7];
        acc0 += w0 * v0 + w2 * v2 + w4 * v4 + w6 * v6;
        acc1 += w1 * v1 + w3 * v3 + w5 * v5 + w7 * v7;
    }
    #pragma unroll
    for (int lg = NFULL * 8; lg < L; lg += 2) {
        f32x4 v0 = __builtin_nontemporal_load(fp + (size_t)lg * 256);
        f32x4 v1 = __builtin_nontemporal_load(fp + (size_t)(lg + 1) * 256);
        acc0 += wgt[lg] * v0;
        acc1 += wgt[lg + 1] * v1;
    }
    f32x4 o = acc0 + acc1;
    if (dst16) {   // panel layout: [(d0>>5)][1024][32]
        half4v h = { f2h(o[0]), f2h(o[1]), f2h(o[2]), f2h(o[3]) };
        *reinterpret_cast<half4v*>(dst16 + ((size_t)(d0 >> 5) * 1024 + b) * 32 + (d0 & 31)) = h;
    }
    if (outa)
        *reinterpret_cast<f32x4*>(outa + (size_t)b * 1024 + d0) = o;
}

// grid 6144 x 128: [0,2048)=rela, [2048,4096)=obj, [4096,6144)=attr.
__global__ __launch_bounds__(128, 1) void att_wsum(
    const float* __restrict__ attr_feats, const float* __restrict__ obj_feats,
    const float* __restrict__ rela_feats,
    const float* __restrict__ attr_masks, const float* __restrict__ att_masks,
    const float* __restrict__ rela_masks,
    const float* __restrict__ scg,
    float* __restrict__ a32,
    _Float16* __restrict__ langA16)
{
    __shared__ float wgt[64];
    const int bid = blockIdx.x;
    const int sub = bid >> 11;
    const int b   = (bid & 2047) >> 1;
    const int dh  = bid & 1;
    if (sub == 0)
        wsum_mod<64>(rela_feats, scg + (size_t)b * 128 + 52, rela_masks + (size_t)b * 64,
                     a32 ? a32 + 2ull * 1024 * 1024 : nullptr,
                     langA16 ? langA16 + 96ull * 1024 * 32 : nullptr, b, dh, wgt);
    else if (sub == 1)
        wsum_mod<36>(obj_feats,  scg + (size_t)b * 128 + 16, att_masks + (size_t)b * 36,
                     a32 ? a32 + 1ull * 1024 * 1024 : nullptr,
                     langA16 ? langA16 + 64ull * 1024 * 32 : nullptr, b, dh, wgt);
    else
        wsum_mod<16>(attr_feats, scg + (size_t)b * 128 + 0,  attr_masks + (size_t)b * 16,
                     a32, langA16 ? langA16 + 32ull * 1024 * 32 : nullptr, b, dh, wgt);
}

// LSTM elementwise; optional f16 panel output.
__global__ __launch_bounds__(256) void lstm4(
    const _Float16* __restrict__ g, size_t zstride, int nz,
    const float* __restrict__ bih, const float* __restrict__ bhh,
    const float* __restrict__ c_prev,
    float* __restrict__ hA, float* __restrict__ hB,
    _Float16* __restrict__ h16,
    float* __restrict__ c_out)
{
    int idx = blockIdx.x * 256 + threadIdx.x;
    int b = idx >> 10, r = idx & 1023;
    size_t base = (size_t)b * 4096;
    float gi = bih[r]        + bhh[r];
    float gf = bih[1024 + r] + bhh[1024 + r];
    float gg = bih[2048 + r] + bhh[2048 + r];
    float go = bih[3072 + r] + bhh[3072 + r];
    for (int z = 0; z < nz; ++z) {
        const _Float16* gz = g + (size_t)z * zstride + base;
        gi += (float)gz[r];
        gf += (float)gz[1024 + r];
        gg += (float)gz[2048 + r];
        go += (float)gz[3072 + r];
    }
    float si = 1.f / (1.f + __expf(-gi));
    float sf = 1.f / (1.f + __expf(-gf));
    float so = 1.f / (1.f + __expf(-go));
    float c2 = sf * c_prev[idx] + si * tanh_fast(gg);
    float h2 = so * tanh_fast(c2);
    hA[idx] = h2;
    if (hB) hB[idx] = h2;
    if (h16) h16[((size_t)(r >> 5) * 1024 + b) * 32 + (r & 31)] = (_Float16)h2;
    c_out[idx] = c2;
}

// ==================== fallback f32-source GEMM (R11) ====================
#define LDSB (128 * 40)
__device__ __forceinline__ void gemm_body(
    _Float16* __restrict__ sm,
    const float* A0, const float* A1, const float* A2p, const float* A3,
    const float* A4,
    const float* W0, const float* W1, const float* W2,
    int w0cols, int w0s, int w1s, int nsel,
    _Float16* __restrict__ Cpart, int ldc,
    int kb, int kLen, int ntile, int mtile, int zout)
{
    _Float16* smA = sm;
    _Float16* smW = sm + 2 * LDSB;
    const int tid  = threadIdx.x;
    const int lane = tid & 63;
    const int wid  = tid >> 6;
    const int wm   = wid >> 1, wn = wid & 1;
    const int m0   = mtile * 128;
    const int n0   = ntile * 128;
    const int nt   = kLen >> 5;
    const int srow = tid >> 3;
    const int scol = (tid & 7) << 2;
    const int fr   = lane & 15;
    const int kq   = lane >> 4;

    const float* wsel = nullptr;
    if (nsel) {
        int sel = n0 >> 9;
        const float* Wq = (sel == 0) ? W0 : (sel == 1) ? W1 : W2;
        wsel = Wq + (size_t)((n0 & 511) + srow) * 1024 + kb + scol;
    }
    f32x4 acc[4][4] = {};
    float4 va[4], vw[4];
    auto LOADA = [&](int lk) {
        int gk = kb + lk;
        int seg = gk >> 10;
        const float* ap = (seg == 0) ? A0 : (seg == 1) ? A1 : (seg == 2) ? A2p
                        : (seg == 3) ? A3 : A4;
        ap += (size_t)(m0 + srow) * 1024 + (gk & 1023) + scol;
        #pragma unroll
        for (int p = 0; p < 4; ++p)
            va[p] = *reinterpret_cast<const float4*>(ap + (size_t)p * 32 * 1024);
    };
    auto LOADW = [&](int lk) {
        const float* wp; int wstr;
        if (nsel) { wp = wsel + lk; wstr = 1024; }
        else {
            int gk = kb + lk;
            if (gk < w0cols) { wp = W0 + (size_t)(n0 + srow) * w0s + gk + scol;            wstr = w0s; }
            else             { wp = W1 + (size_t)(n0 + srow) * w1s + (gk - w0cols) + scol; wstr = w1s; }
        }
        #pragma unroll
        for (int p = 0; p < 4; ++p)
            vw[p] = *reinterpret_cast<const float4*>(wp + (size_t)p * 32 * wstr);
    };
    auto WRITEA = [&](int buf) {
        _Float16* d = smA + buf * LDSB;
        #pragma unroll
        for (int p = 0; p < 4; ++p) {
            half4v h = { f2h(va[p].x), f2h(va[p].y), f2h(va[p].z), f2h(va[p].w) };
            *reinterpret_cast<half4v*>(&d[(srow + p * 32) * 40 + scol]) = h;
        }
    };
    auto WRITEW = [&](int buf) {
        _Float16* d = smW + buf * LDSB;
        #pragma unroll
        for (int p = 0; p < 4; ++p) {
            half4v h = { f2h(vw[p].x), f2h(vw[p].y), f2h(vw[p].z), f2h(vw[p].w) };
            *reinterpret_cast<half4v*>(&d[(srow + p * 32) * 40 + scol]) = h;
        }
    };
    auto DOMFMA = [&](int buf) {
        half8 af[4], bf[4];
        _Float16* sA = smA + buf * LDSB;
        _Float16* sW = smW + buf * LDSB;
        #pragma unroll
        for (int i = 0; i < 4; ++i) {
            af[i] = *reinterpret_cast<const half8*>(&sA[(wm * 64 + i * 16 + fr) * 40 + kq * 8]);
            bf[i] = *reinterpret_cast<const half8*>(&sW[(wn * 64 + i * 16 + fr) * 40 + kq * 8]);
        }
        #pragma unroll
        for (int i = 0; i < 4; ++i)
            #pragma unroll
            for (int j = 0; j < 4; ++j)
                acc[i][j] = __builtin_amdgcn_mfma_f32_16x16x32_f16(af[i], bf[j], acc[i][j], 0, 0, 0);
    };
    LOADA(0); LOADW(0);
    WRITEA(0); WRITEW(0);
    __syncthreads();
    int cur = 0;
    for (int it = 0; it < nt - 1; ++it) {
        LOADA((it + 1) * 32);
        LOADW((it + 1) * 32);
        DOMFMA(cur);
        WRITEA(cur ^ 1);
        WRITEW(cur ^ 1);
        __syncthreads();
        cur ^= 1;
    }
    DOMFMA(cur);
    _Float16* cp = Cpart + (size_t)zout * 1024ull * (size_t)ldc;
    #pragma unroll
    for (int j = 0; j < 4; ++j) {
        int nc = n0 + wn * 64 + j * 16 + fr;
        #pragma unroll
        for (int i = 0; i < 4; ++i) {
            int rb = m0 + wm * 64 + i * 16 + kq * 4;
            #pragma unroll
            for (int r = 0; r < 4; ++r)
                cp[(size_t)(rb + r) * ldc + nc] = (_Float16)acc[i][j][r];
        }
    }
}

__global__ __launch_bounds__(256) void gemm_hf(
    const float* A0, const float* A1, const float* A2p, const float* A3,
    const float* A4,
    const float* W0, const float* W1, const float* W2,
    int w0cols, int w0s, int w1s, int nsel,
    _Float16* Cpart, int ldc, int kLen, int zbase)
{
    __shared__ _Float16 sm[4 * LDSB];
    gemm_body(sm, A0, A1, A2p, A3, A4, W0, W1, W2, w0cols, w0s, w1s, nsel,
              Cpart, ldc, blockIdx.z * kLen, kLen,
              blockIdx.x, blockIdx.y, zbase + blockIdx.z);
}

extern "C" void kernel_launch(void* const* d_in, const int* in_sizes, int n_in,
                              void* d_out, int out_size, void* d_ws, size_t ws_size,
                              hipStream_t stream)
{
    const size_t BR = 1024ull * 1024ull;
    const float* xt         = (const float*)d_in[0];
    const float* fc         = (const float*)d_in[1];
    const float* state_h    = (const float*)d_in[2];
    const float* state_c    = (const float*)d_in[3];
    const float* attr_feats = (const float*)d_in[4];
    const float* obj_feats  = (const float*)d_in[5];
    const float* rela_feats = (const float*)d_in[6];
    const float* p_attr     = (const float*)d_in[7];
    const float* p_obj      = (const float*)d_in[8];
    const float* p_rela     = (const float*)d_in[9];
    const float* attr_masks = (const float*)d_in[10];
    const float* att_masks  = (const float*)d_in[11];
    const float* rela_masks = (const float*)d_in[12];
    const float* att_Wih    = (const float*)d_in[13];
    const float* att_Whh    = (const float*)d_in[14];
    const float* att_bih    = (const float*)d_in[15];
    const float* att_bhh    = (const float*)d_in[16];
    const float* lang_Wih   = (const float*)d_in[17];
    const float* lang_Whh   = (const float*)d_in[18];
    const float* lang_bih   = (const float*)d_in[19];
    const float* lang_bhh   = (const float*)d_in[20];
    const float* attr_Wq    = (const float*)d_in[21];
    const float* attr_bq    = (const float*)d_in[22];
    const float* attr_wa    = (const float*)d_in[23];
    const float* attr_ba    = (const float*)d_in[24];
    const float* obj_Wq     = (const float*)d_in[25];
    const float* obj_bq     = (const float*)d_in[26];
    const float* obj_wa     = (const float*)d_in[27];
    const float* obj_ba     = (const float*)d_in[28];
    const float* rela_Wq    = (const float*)d_in[29];
    const float* rela_bq    = (const float*)d_in[30];
    const float* rela_wa    = (const float*)d_in[31];
    const float* rela_ba    = (const float*)d_in[32];

    float* out = (float*)d_out;
    const float* h0 = state_h;
    const float* h1 = state_h + BR;
    float* h_att = out + BR;
    float* scg  = out;   // scratch in out slot 0 (fully rewritten by final lstm4)

    dim3 blk(256);

    // -------- pre-mode: f16 panel-packed operands (needs 131 MiB ws) --------
    const bool pre = ws_size >= 137363456ull;
    if (pre) {
        _Float16* g16     = (_Float16*)d_ws;                  // 16M f16
        _Float16* q16     = g16     + 16ull * BR;             // 3M
        _Float16* attW16  = q16     + 3ull  * BR;             // 16M
        _Float16* langW16 = attW16  + 16ull * BR;             // 20M
        _Float16* qW16    = langW16 + 20ull * BR;             // 1.5M
        _Float16* attA16  = qW16    + 1536ull * 1024;         // 4M
        _Float16* langA16 = attA16  + 4ull  * BR;             // 5M

        pack_all<<<dim3(21760), blk, 0, stream>>>(
            att_Wih, att_Whh, lang_Wih, lang_Whh,
            attr_Wq, obj_Wq, rela_Wq,
            h1, fc, xt, h0,
            attW16, langW16, qW16, attA16, langA16);
        gemm16b<<<dim3(32, 4, 4), blk, 0, stream>>>(
            attA16, 1024, attW16, 4096, g16, 4096, 1024);
        lstm4<<<dim3(4096), blk, 0, stream>>>(
            g16, 4ull * BR, 4, att_bih, att_bhh, state_c,
            h_att, nullptr, langA16, out + 3 * BR);
        gemm16<<<dim3(12, 8, 2), blk, 0, stream>>>(
            langA16, 1024, qW16, 1536, q16, 1536, 512);
        att_scores<<<dim3(29696), blk, 0, stream>>>(
            p_attr, p_obj, p_rela, q16,
            attr_bq, obj_bq, rela_bq, attr_wa, obj_wa, rela_wa,
            attr_ba, obj_ba, rela_ba, scg);
        att_wsum<<<dim3(6144), dim3(128), 0, stream>>>(
            attr_feats, obj_feats, rela_feats,
            attr_masks, att_masks, rela_masks, scg, nullptr, langA16);
        gemm16b<<<dim3(32, 4, 4), blk, 0, stream>>>(
            langA16, 1024, langW16, 4096, g16, 4096, 1280);
        lstm4<<<dim3(4096), blk, 0, stream>>>(
            g16, 4ull * BR, 4, lang_bih, lang_bhh, state_c + BR,
            out, out + 2 * BR, nullptr, out + 4 * BR);
        return;
    }

    // -------- fallback: R11 path --------
    const bool big = ws_size >= 52428800ull;
    const int gslots = big ? 4 : 2;
    _Float16* g16 = (_Float16*)d_ws;
    _Float16* q16 = g16 + (size_t)gslots * 4ull * BR;
    float*    a32 = (float*)(q16 + 2ull * 1536 * 1024);
    float* a_attr = a32;
    float* a_obj  = a32 + BR;
    float* a_rela = a32 + 2 * BR;
    const int zsplit = big ? 4 : 2;

    gemm_hf<<<dim3(32, 8, zsplit), blk, 0, stream>>>(
        h1, fc, xt, h0, h0, att_Wih, att_Whh, att_Whh,
        3072, 3072, 1024, 0, g16, 4096, 4096 / zsplit, 0);
    lstm4<<<dim3(4096), blk, 0, stream>>>(
        g16, 4ull * BR, gslots, att_bih, att_bhh, state_c,
        h_att, nullptr, nullptr, out + 3 * BR);
    gemm_hf<<<dim3(12, 8, 2), blk, 0, stream>>>(
        h_att, h_att, h_att, h_att, h_att,
        attr_Wq, obj_Wq, rela_Wq, 0, 1024, 1024, 1,
        q16, 1536, 512, 0);
    att_scores<<<dim3(29696), blk, 0, stream>>>(
        p_attr, p_obj, p_rela, q16,
        attr_bq, obj_bq, rela_bq, attr_wa, obj_wa, rela_wa,
        attr_ba, obj_ba, rela_ba, scg);
    att_wsum<<<dim3(6144), dim3(128), 0, stream>>>(
        attr_feats, obj_feats, rela_feats,
        attr_masks, att_masks, rela_masks, scg, a32, nullptr);
    gemm_hf<<<dim3(32, 8, zsplit), blk, 0, stream>>>(
        h_att, a_attr, a_obj, a_rela, h1,
        lang_Wih, lang_Whh, lang_Whh, 4096, 4096, 1024, 0,
        g16, 4096, 5120 / zsplit, 0);
    lstm4<<<dim3(4096), blk, 0, stream>>>(
        g16, 4ull * BR, gslots, lang_bih, lang_bhh, state_c + BR,
        out, out + 2 * BR, nullptr, out + 4 * BR);
}